// Round 8
// baseline (1016.922 us; speedup 1.0000x reference)
//
#include <hip/hip_runtime.h>
#include <stdint.h>

// Problem: B=8, Lq=Lv=2048, Din=Dout=512, all f32 in/out.
// out[b][l][0:512)=o, [512:1024)=q, [1024:1536)=mv broadcast.
// Flash v8: 32x32x16 MFMA (2x FLOP/LDS-byte), 32 q-rows/wave, 4 waves =
// 2 row-groups x 2 KV-streams, single-buffered per stream, in-block merge.

typedef __attribute__((ext_vector_type(8))) short short8v;
typedef __attribute__((ext_vector_type(4))) float f32x4;
typedef __attribute__((ext_vector_type(16))) float f32x16;

#define LQ 2048
#define LV 2048
#define DIN 512
#define DOUT 512
#define NB 8
#define KT 32   // KV tile

__device__ __forceinline__ unsigned short f2bf(float x){
    union { float f; unsigned u; } v; v.f = x;
    unsigned r = v.u + 0x7fffu + ((v.u >> 16) & 1u);
    return (unsigned short)(r >> 16);
}

// async global->LDS, 16B per lane; LDS dest = wave-uniform base + lane*16
__device__ __forceinline__ void gload16(const void* g, void* l){
    __builtin_amdgcn_global_load_lds((const __attribute__((address_space(1))) void*)g,
                                     (__attribute__((address_space(3))) void*)l, 16, 0, 0);
}

#define SBAR   do{ __builtin_amdgcn_s_barrier(); __builtin_amdgcn_sched_barrier(0); }while(0)
#define VMCNT0 do{ asm volatile("s_waitcnt vmcnt(0)" ::: "memory"); \
                   __builtin_amdgcn_sched_barrier(0); }while(0)

// kernel [DIN][DOUT] f32 -> kT [DOUT][DIN] bf16, scaled by 0.1 (folds the /10)
__global__ void prep_kT(const float* __restrict__ k, unsigned short* __restrict__ kT){
    __shared__ float tile[32][33];
    int tx = threadIdx.x & 31, ty = threadIdx.x >> 5;
    int kb = blockIdx.x, eb = blockIdx.y;
    #pragma unroll
    for (int p = 0; p < 4; ++p){
        int r = ty + p*8;
        tile[r][tx] = k[(size_t)(kb*32 + r)*DOUT + eb*32 + tx];
    }
    __syncthreads();
    #pragma unroll
    for (int p = 0; p < 4; ++p){
        int r = ty + p*8;
        kT[(size_t)(eb*32 + r)*DIN + kb*32 + tx] = f2bf(tile[tx][r] * 0.1f);
    }
}

// v f32 -> v bf16 (natural [b][j][e]) and vT bf16 ([b][e][j]) + masked-max partials
__global__ void prep_v(const float* __restrict__ v, const float* __restrict__ mask,
                       unsigned short* __restrict__ vbf, unsigned short* __restrict__ vT,
                       float* __restrict__ part){
    __shared__ float tile[32][33];
    __shared__ float pmax_l[8][33];
    int tx = threadIdx.x & 31, ty = threadIdx.x >> 5;
    int jb = blockIdx.x, eb = blockIdx.y, b = blockIdx.z;
    const size_t vbase = (size_t)b*LV*DOUT;
    #pragma unroll
    for (int p = 0; p < 4; ++p){
        int r = ty + p*8;
        size_t idx = vbase + (size_t)(jb*32 + r)*DOUT + eb*32 + tx;
        float val = v[idx];
        tile[r][tx] = val;
        vbf[idx] = f2bf(val);
    }
    __syncthreads();
    const size_t tbase = (size_t)b*DOUT*LV;
    #pragma unroll
    for (int p = 0; p < 4; ++p){
        int r = ty + p*8;
        vT[tbase + (size_t)(eb*32 + r)*LV + jb*32 + tx] = f2bf(tile[tx][r]);
    }
    float m = -3e38f;
    #pragma unroll
    for (int k2 = 0; k2 < 4; ++k2){
        int j = ty*4 + k2;
        float msk = mask[b*LV + jb*32 + j];
        m = fmaxf(m, tile[j][tx] - (1.0f - msk)*1e10f);
    }
    pmax_l[ty][tx] = m;
    __syncthreads();
    if (ty == 0){
        float mm = pmax_l[0][tx];
        #pragma unroll
        for (int c = 1; c < 8; ++c) mm = fmaxf(mm, pmax_l[c][tx]);
        part[((size_t)b*64 + jb)*DOUT + eb*32 + tx] = mm;
    }
}

__global__ void mv_final(const float* __restrict__ part, float* __restrict__ mv){
    int b = blockIdx.x; int e = threadIdx.x;
    float m = -3e38f;
    #pragma unroll
    for (int c = 0; c < 64; ++c) m = fmaxf(m, part[((size_t)b*64 + c)*DOUT + e]);
    mv[b*DOUT + e] = m;
}

// qw[b*Lq+l][e] = sum_d q[..][d] * kT[e][d]  (bf16 MFMA, f32 acc, bf16 out)
__global__ __launch_bounds__(256) void gemm_qw(const float* __restrict__ q,
                                               const unsigned short* __restrict__ kT,
                                               unsigned short* __restrict__ qw){
    int bid = blockIdx.x;
    int mb = bid >> 1, nb = bid & 1;
    int w = threadIdx.x >> 6, lane = threadIdx.x & 63;
    int li = lane & 15, lg = lane >> 4;
    int i0 = mb*64 + w*16;
    int n0 = nb*256;
    f32x4 acc[16];
    #pragma unroll
    for (int t = 0; t < 16; ++t) acc[t] = (f32x4){0.f,0.f,0.f,0.f};
    for (int ks = 0; ks < 16; ++ks){
        const float* qp = q + (size_t)(i0 + li)*DIN + ks*32 + lg*8;
        float4 lo = *(const float4*)qp;
        float4 hi = *(const float4*)(qp + 4);
        short8v af;
        af[0]=(short)f2bf(lo.x); af[1]=(short)f2bf(lo.y); af[2]=(short)f2bf(lo.z); af[3]=(short)f2bf(lo.w);
        af[4]=(short)f2bf(hi.x); af[5]=(short)f2bf(hi.y); af[6]=(short)f2bf(hi.z); af[7]=(short)f2bf(hi.w);
        #pragma unroll
        for (int t = 0; t < 16; ++t){
            short8v bf = *(const short8v*)(kT + (size_t)(n0 + t*16 + li)*DIN + ks*32 + lg*8);
            acc[t] = __builtin_amdgcn_mfma_f32_16x16x32_bf16(af, bf, acc[t], 0, 0, 0);
        }
    }
    #pragma unroll
    for (int t = 0; t < 16; ++t)
        #pragma unroll
        for (int r = 0; r < 4; ++r)
            qw[(size_t)(i0 + 4*lg + r)*DOUT + n0 + t*16 + li] = f2bf(acc[t][r]);
}

// Flash v8.
// Wave roles: st = w>>1 (KV stream: tiles st*32 .. st*32+31), rw = w&1
// (row group: rows i0 + rw*32 .. +31). Streams have private single-buffered
// A (32KB, [j][e] swizzled unit^(j&7)) and T (32KB, [e][j] swizzled
// unit^((e>>1)&3)) tiles. End: 2-way softmax merge across stream pairs.
// MFMA 32x32x16: C/D row=(reg&3)+8*(reg>>2)+4*(lane>>5), col=lane&31 (m101);
// A: row m=lane&31, k=(lane>>5)*8..+7; B: col n=lane&31, k=(lane>>5)*8..+7.
__global__ __launch_bounds__(256, 1) void flash(const unsigned short* __restrict__ qw,
                                                const unsigned short* __restrict__ vbf,
                                                const unsigned short* __restrict__ vT,
                                                const float* __restrict__ mask,
                                                const float* __restrict__ qf32,
                                                const float* __restrict__ mv,
                                                float* __restrict__ out){
    __shared__ __align__(16) char LDS[150528];
    // [0,64K): stream0 A+T; [64K,128K): stream1 A+T; [128K,136K): mask;
    // [136K+..): P (4 x 2560B); tail: red_m/red_s. Obuf reuses tile regions.

    const int bid = blockIdx.x;
    const int b = bid & 7, qt = bid >> 3;   // batch -> XCD pin
    const int tid = threadIdx.x;
    const int w = tid >> 6, lane = tid & 63;
    const int e5 = lane & 31, hs = lane >> 5;
    const int st = w >> 1, rw = w & 1;
    const int i0 = qt*64;

    short* A = (short*)(LDS + st*65536);
    short* T = (short*)(LDS + st*65536 + 32768);
    float* maskL = (float*)(LDS + 131072);
    unsigned* Pw = (unsigned*)(LDS + 139264 + w*2560);  // [32 rows][20 u32]
    float* redm = (float*)(LDS + 149504);
    float* reds = (float*)(LDS + 150016);

    const unsigned short* vb  = vbf + (size_t)b*LV*DOUT;
    const unsigned short* vTb = vT  + (size_t)b*DOUT*LV;
    const float* mkb = mask + b*LV;

    // q B-fragments: lane holds col i = i0+rw*32+e5, k-span ks*16+hs*8..+7
    short8v qf[32];
    {
        const unsigned short* qrow = qw + (size_t)(b*LQ + i0 + rw*32 + e5)*DIN;
        #pragma unroll
        for (int ks = 0; ks < 32; ++ks)
            qf[ks] = *(const short8v*)(qrow + ks*16 + hs*8);
    }

    // staging: one gload = one A row (1KB) / 16 T rows (64B each).
    // A: position unit `lane` <- global unit lane^(j&7) (read: (ks*2+hs)^(j&7))
    // T: position unit lane&3 <- global unit (lane&3)^((e>>1)&3)
    auto stage = [&](int j0g){
        #pragma unroll
        for (int p = 0; p < 16; ++p){
            int j = rw*16 + p;
            gload16(vb + (size_t)(j0g + j)*DOUT + ((lane ^ (j&7))*8), (char*)A + j*1024);
        }
        #pragma unroll
        for (int p = 0; p < 16; ++p){
            int e0 = rw*256 + p*16;
            int e  = e0 + (lane >> 2);
            gload16(vTb + (size_t)e*LV + j0g + (((lane&3) ^ ((e>>1)&3))*8), (char*)T + e0*64);
        }
    };

    f32x16 acc[16];
    #pragma unroll
    for (int t = 0; t < 16; ++t)
        #pragma unroll
        for (int r = 0; r < 16; ++r) acc[t][r] = 0.f;
    float mrun = -1e30f, srun = 0.f;

    stage((st*32)*KT);
    gload16(mkb + (w*2+0)*256 + lane*4, (char*)maskL + (w*2+0)*1024);
    gload16(mkb + (w*2+1)*256 + lane*4, (char*)maskL + (w*2+1)*1024);
    VMCNT0; SBAR;

    const int key8 = e5 & 7;        // A swizzle key (this lane's j row)
    const int keyT = (e5 >> 1) & 3; // T swizzle key (e low bits; nt*32 doesn't affect)

    for (int jtn = 0; jtn < 32; ++jtn){
        const int j0 = (st*32 + jtn)*KT;

        // S^T: D[m=j][n=i] = sum_e v[j][e] q[i][e]; one 32x32 tile, K=512
        f32x16 s1;
        #pragma unroll
        for (int r = 0; r < 16; ++r) s1[r] = 0.f;
        __builtin_amdgcn_s_setprio(1);
        #pragma unroll
        for (int ks = 0; ks < 32; ++ks){
            short8v a = *(const short8v*)&A[e5*512 + (((ks*2 + hs) ^ key8)*8)];
            s1 = __builtin_amdgcn_mfma_f32_32x32x16_bf16(a, qf[ks], s1, 0, 0, 0);
        }
        __builtin_amdgcn_s_setprio(0);

        // bias + softmax; lane e5 = q-row i; reg r -> j = (r&3)+8*(r>>2)+4*hs
        float sv[16];
        #pragma unroll
        for (int rq = 0; rq < 4; ++rq){
            f32x4 mk = *(const f32x4*)&maskL[j0 + 8*rq + 4*hs];
            #pragma unroll
            for (int k = 0; k < 4; ++k)
                sv[rq*4 + k] = s1[rq*4 + k] + (mk[k] - 1.0f)*1e10f;
        }
        float pmax = sv[0];
        #pragma unroll
        for (int k = 1; k < 16; ++k) pmax = fmaxf(pmax, sv[k]);
        pmax = fmaxf(pmax, __shfl_xor(pmax, 32));
        float mnew = fmaxf(mrun, pmax);
        float al = __expf(mrun - mnew);
        float p[16]; float psum = 0.f;
        #pragma unroll
        for (int k = 0; k < 16; ++k){ p[k] = __expf(sv[k] - mnew); psum += p[k]; }
        psum += __shfl_xor(psum, 32);
        srun = srun*al + psum; mrun = mnew;

        if (!__all(al == 1.0f)){
            float alr[16];
            #pragma unroll
            for (int r = 0; r < 16; ++r)
                alr[r] = __shfl(al, (r&3) + 8*(r>>2) + 4*hs);  // acc row i_r
            #pragma unroll
            for (int t = 0; t < 16; ++t)
                #pragma unroll
                for (int r = 0; r < 16; ++r) acc[t][r] *= alr[r];
        }

        // P pack -> LDS [i][j/2], slot = (r&2)/2 + 4*(r>>2) + 2*hs
        #pragma unroll
        for (int r = 0; r < 16; r += 2){
            unsigned pk = (unsigned)f2bf(p[r]) | ((unsigned)f2bf(p[r+1]) << 16);
            Pw[e5*20 + (((r&2)>>1) + 4*(r>>2) + 2*hs)] = pk;
        }
        // PV A-frags: row i=e5, k=j: kk*16+hs*8..+7 -> u32 slots kk*8+hs*4..+3
        short8v pa0 = *(const short8v*)&Pw[e5*20 + hs*4];        // same-wave RAW
        short8v pa1 = *(const short8v*)&Pw[e5*20 + 8 + hs*4];

        // PV: D[m=i][n=e], 16 e-tiles x (K=32 -> 2 MFMA)
        __builtin_amdgcn_s_setprio(1);
        #pragma unroll
        for (int nt = 0; nt < 16; ++nt){
            short8v vf0 = *(const short8v*)&T[(nt*32 + e5)*32 + ((hs ^ keyT)*8)];
            acc[nt] = __builtin_amdgcn_mfma_f32_32x32x16_bf16(pa0, vf0, acc[nt], 0, 0, 0);
            short8v vf1 = *(const short8v*)&T[(nt*32 + e5)*32 + (((2 + hs) ^ keyT)*8)];
            acc[nt] = __builtin_amdgcn_mfma_f32_32x32x16_bf16(pa1, vf1, acc[nt], 0, 0, 0);
        }
        __builtin_amdgcn_s_setprio(0);

        SBAR;                                   // all reads of this buffer done
        if (jtn + 1 < 32){ stage((st*32 + jtn + 1)*KT); VMCNT0; }
        SBAR;                                   // buffers refilled for all
    }

    // ---- 2-way merge across stream pairs (w <-> w^2 share rows) ----
    if (hs == 0){ redm[w*32 + e5] = mrun; reds[w*32 + e5] = srun; }
    SBAR;
    float f[16];
    #pragma unroll
    for (int r = 0; r < 16; ++r){
        int ir = (r&3) + 8*(r>>2) + 4*hs;
        float mw = redm[w*32 + ir],       sw = reds[w*32 + ir];
        float mp = redm[(w^2)*32 + ir],   sp = reds[(w^2)*32 + ir];
        float mg = fmaxf(mw, mp);
        float sg = sw*__expf(mw - mg) + sp*__expf(mp - mg);
        f[r] = __expf(mw - mg) / sg;     // includes final 1/s
    }
    float* Obuf = (float*)(LDS + rw*65536);   // pair's 32 rows x 512 f32 = 64KB
    if (st == 1){
        #pragma unroll
        for (int nt = 0; nt < 16; ++nt)
            #pragma unroll
            for (int r = 0; r < 16; ++r){
                int rl = (r&3) + 8*(r>>2) + 4*hs;
                Obuf[rl*512 + nt*32 + e5] = acc[nt][r]*f[r];
            }
    }
    SBAR;
    if (st == 0){
        #pragma unroll
        for (int nt = 0; nt < 16; ++nt)
            #pragma unroll
            for (int r = 0; r < 16; ++r){
                int rl = (r&3) + 8*(r>>2) + 4*hs;
                float val = acc[nt][r]*f[r] + Obuf[rl*512 + nt*32 + e5];
                out[(size_t)(b*LQ + i0 + rw*32 + rl)*1536 + nt*32 + e5] = val;
            }
    } else {
        // q passthrough + mv broadcast for this block's 64 rows (waves 2,3)
        const float4* q4  = (const float4*)qf32;
        const float4* mv4 = (const float4*)mv;
        float4* o4 = (float4*)out;
        int t2 = (w - 2)*64 + lane;   // 0..127
        for (int idx = t2; idx < 64*256; idx += 128){
            int row = idx >> 8, c = idx & 255;
            size_t grow = (size_t)b*LQ + i0 + row;
            if (c < 128) o4[grow*384 + 128 + c] = q4[grow*128 + c];
            else         o4[grow*384 + 256 + (c - 128)] = mv4[b*128 + (c - 128)];
        }
    }
}

extern "C" void kernel_launch(void* const* d_in, const int* in_sizes, int n_in,
                              void* d_out, int out_size, void* d_ws, size_t ws_size,
                              hipStream_t stream){
    const float* q     = (const float*)d_in[0];
    const float* v     = (const float*)d_in[1];
    const float* vmask = (const float*)d_in[2];
    const float* kern  = (const float*)d_in[3];
    float* out = (float*)d_out;
    char* ws = (char*)d_ws;

    const size_t SZ_QW = (size_t)NB*LQ*DOUT*2;       // 16 MB
    unsigned short* qw  = (unsigned short*)(ws);
    unsigned short* vbf = (unsigned short*)(ws + SZ_QW);
    unsigned short* vT  = (unsigned short*)(ws + 2*SZ_QW);
    unsigned short* kT  = (unsigned short*)(ws + 3*SZ_QW);
    float* mv   = (float*)(ws + 3*SZ_QW + 524288);
    float* part = (float*)(ws + 3*SZ_QW + 524288 + 16384);

    hipLaunchKernelGGL(prep_kT,  dim3(16,16),   dim3(256), 0, stream, kern, kT);
    hipLaunchKernelGGL(prep_v,   dim3(64,16,8), dim3(256), 0, stream, v, vmask, vbf, vT, part);
    hipLaunchKernelGGL(mv_final, dim3(8),       dim3(512), 0, stream, part, mv);
    hipLaunchKernelGGL(gemm_qw,  dim3(512),     dim3(256), 0, stream, q, kT, qw);
    hipLaunchKernelGGL(flash,    dim3(256),     dim3(256), 0, stream, qw, vbf, vT, vmask, q, mv, out);
}

// Round 9
// 302.415 us; speedup vs baseline: 3.3627x; 3.3627x over previous
//
#include <hip/hip_runtime.h>
#include <stdint.h>

// Problem: B=8, Lq=Lv=2048, Din=Dout=512, all f32 in/out.
// out[b][l][0:512)=o, [512:1024)=q, [1024:1536)=mv broadcast.
// Flash v9 = r7 base + (a) T-tile both-sides swizzle (kills 8-way conflict)
//          + (b) P-broadcast PV: each wave computes ALL 64 rows x its 128-e
//            quarter; PV LDS reads 32 -> 12 per wave per jt.

typedef __attribute__((ext_vector_type(8))) short short8v;
typedef __attribute__((ext_vector_type(4))) float f32x4;

#define LQ 2048
#define LV 2048
#define DIN 512
#define DOUT 512
#define NB 8
#define KT 32   // KV tile

__device__ __forceinline__ unsigned short f2bf(float x){
    union { float f; unsigned u; } v; v.f = x;
    unsigned r = v.u + 0x7fffu + ((v.u >> 16) & 1u);
    return (unsigned short)(r >> 16);
}

__device__ __forceinline__ void gload16(const void* g, void* l){
    __builtin_amdgcn_global_load_lds((const __attribute__((address_space(1))) void*)g,
                                     (__attribute__((address_space(3))) void*)l, 16, 0, 0);
}

#define SBAR    do{ __builtin_amdgcn_s_barrier(); __builtin_amdgcn_sched_barrier(0); }while(0)
#define VMCNT16 do{ asm volatile("s_waitcnt vmcnt(16)" ::: "memory"); \
                    __builtin_amdgcn_sched_barrier(0); }while(0)
#define VMCNT0  do{ asm volatile("s_waitcnt vmcnt(0)" ::: "memory"); \
                    __builtin_amdgcn_sched_barrier(0); }while(0)

// kernel [DIN][DOUT] f32 -> kT [DOUT][DIN] bf16, scaled by 0.1 (folds the /10)
__global__ void prep_kT(const float* __restrict__ k, unsigned short* __restrict__ kT){
    __shared__ float tile[32][33];
    int tx = threadIdx.x & 31, ty = threadIdx.x >> 5;
    int kb = blockIdx.x, eb = blockIdx.y;
    #pragma unroll
    for (int p = 0; p < 4; ++p){
        int r = ty + p*8;
        tile[r][tx] = k[(size_t)(kb*32 + r)*DOUT + eb*32 + tx];
    }
    __syncthreads();
    #pragma unroll
    for (int p = 0; p < 4; ++p){
        int r = ty + p*8;
        kT[(size_t)(eb*32 + r)*DIN + kb*32 + tx] = f2bf(tile[tx][r] * 0.1f);
    }
}

// v f32 -> v bf16 (natural [b][j][e]) and vT bf16 ([b][e][j]) + masked-max partials
__global__ void prep_v(const float* __restrict__ v, const float* __restrict__ mask,
                       unsigned short* __restrict__ vbf, unsigned short* __restrict__ vT,
                       float* __restrict__ part){
    __shared__ float tile[32][33];
    __shared__ float pmax_l[8][33];
    int tx = threadIdx.x & 31, ty = threadIdx.x >> 5;
    int jb = blockIdx.x, eb = blockIdx.y, b = blockIdx.z;
    const size_t vbase = (size_t)b*LV*DOUT;
    #pragma unroll
    for (int p = 0; p < 4; ++p){
        int r = ty + p*8;
        size_t idx = vbase + (size_t)(jb*32 + r)*DOUT + eb*32 + tx;
        float val = v[idx];
        tile[r][tx] = val;
        vbf[idx] = f2bf(val);
    }
    __syncthreads();
    const size_t tbase = (size_t)b*DOUT*LV;
    #pragma unroll
    for (int p = 0; p < 4; ++p){
        int r = ty + p*8;
        vT[tbase + (size_t)(eb*32 + r)*LV + jb*32 + tx] = f2bf(tile[tx][r]);
    }
    float m = -3e38f;
    #pragma unroll
    for (int k2 = 0; k2 < 4; ++k2){
        int j = ty*4 + k2;
        float msk = mask[b*LV + jb*32 + j];
        m = fmaxf(m, tile[j][tx] - (1.0f - msk)*1e10f);
    }
    pmax_l[ty][tx] = m;
    __syncthreads();
    if (ty == 0){
        float mm = pmax_l[0][tx];
        #pragma unroll
        for (int c = 1; c < 8; ++c) mm = fmaxf(mm, pmax_l[c][tx]);
        part[((size_t)b*64 + jb)*DOUT + eb*32 + tx] = mm;
    }
}

__global__ void mv_final(const float* __restrict__ part, float* __restrict__ mv){
    int b = blockIdx.x; int e = threadIdx.x;
    float m = -3e38f;
    #pragma unroll
    for (int c = 0; c < 64; ++c) m = fmaxf(m, part[((size_t)b*64 + c)*DOUT + e]);
    mv[b*DOUT + e] = m;
}

// qw[b*Lq+l][e] = sum_d q[..][d] * kT[e][d]  (bf16 MFMA, f32 acc, bf16 out)
__global__ __launch_bounds__(256) void gemm_qw(const float* __restrict__ q,
                                               const unsigned short* __restrict__ kT,
                                               unsigned short* __restrict__ qw){
    int bid = blockIdx.x;
    int mb = bid >> 1, nb = bid & 1;
    int w = threadIdx.x >> 6, lane = threadIdx.x & 63;
    int li = lane & 15, lg = lane >> 4;
    int i0 = mb*64 + w*16;
    int n0 = nb*256;
    f32x4 acc[16];
    #pragma unroll
    for (int t = 0; t < 16; ++t) acc[t] = (f32x4){0.f,0.f,0.f,0.f};
    for (int ks = 0; ks < 16; ++ks){
        const float* qp = q + (size_t)(i0 + li)*DIN + ks*32 + lg*8;
        float4 lo = *(const float4*)qp;
        float4 hi = *(const float4*)(qp + 4);
        short8v af;
        af[0]=(short)f2bf(lo.x); af[1]=(short)f2bf(lo.y); af[2]=(short)f2bf(lo.z); af[3]=(short)f2bf(lo.w);
        af[4]=(short)f2bf(hi.x); af[5]=(short)f2bf(hi.y); af[6]=(short)f2bf(hi.z); af[7]=(short)f2bf(hi.w);
        #pragma unroll
        for (int t = 0; t < 16; ++t){
            short8v bf = *(const short8v*)(kT + (size_t)(n0 + t*16 + li)*DIN + ks*32 + lg*8);
            acc[t] = __builtin_amdgcn_mfma_f32_16x16x32_bf16(af, bf, acc[t], 0, 0, 0);
        }
    }
    #pragma unroll
    for (int t = 0; t < 16; ++t)
        #pragma unroll
        for (int r = 0; r < 4; ++r)
            qw[(size_t)(i0 + 4*lg + r)*DOUT + n0 + t*16 + li] = f2bf(acc[t][r]);
}

__global__ __launch_bounds__(256, 1) void flash(const unsigned short* __restrict__ qw,
                                                const unsigned short* __restrict__ vbf,
                                                const unsigned short* __restrict__ vT,
                                                const float* __restrict__ mask,
                                                const float* __restrict__ qf32,
                                                const float* __restrict__ mv,
                                                float* __restrict__ out){
    __shared__ __align__(16) short A_t[2][KT*512];   // 2x32KB, [j][e] unit^(j&7)
    __shared__ __align__(16) short T_t[2][512*KT];   // 2x32KB, [e][j] slot^((e>>1)&3)
    __shared__ __align__(16) float maskL[2048];      // 8KB mask row
    __shared__ short P_lds[4][16][40];               // P[w-rows][j], 80B stride
    __shared__ float alB[64], sB[64];
    __shared__ int   flagB[4];

    const int bid = blockIdx.x;
    const int b = bid & 7, qt = bid >> 3;   // batch -> XCD pin
    const int tid = threadIdx.x;
    const int w = tid >> 6, lane = tid & 63;
    const int li = lane & 15, lg = lane >> 4;
    const int i0 = qt*64;

    const unsigned short* vb  = vbf + (size_t)b*LV*DOUT;
    const unsigned short* vTb = vT  + (size_t)b*DOUT*LV;
    const float* mkb = mask + b*LV;

    // q B-fragments for THIS wave's 16 softmax-owned rows (i = i0+w*16+li)
    short8v qf[16];
    const unsigned short* qrow = qw + (size_t)(b*LQ + i0 + w*16 + li)*DIN;
    #pragma unroll
    for (int ks = 0; ks < 16; ++ks)
        qf[ks] = *(const short8v*)(qrow + ks*32 + lg*8);

    // staging (16 gload16/wave/tile); A as r7 (verified); T with read-matching swizzle
    auto stage = [&](int j0g, int bufsel){
        #pragma unroll
        for (int p = 0; p < 8; ++p){
            int j = w*8 + p;
            gload16(vb + (size_t)(j0g + j)*DOUT + ((lane ^ (j&7))*8), &A_t[bufsel][j*512]);
        }
        #pragma unroll
        for (int p = 0; p < 8; ++p){
            int e0 = w*128 + p*16;
            int e  = e0 + (lane >> 2);
            gload16(vTb + (size_t)e*LV + j0g + (((lane&3) ^ ((lane>>3)&3))*8),
                    &T_t[bufsel][e0*KT]);
        }
    };

    // acc: 64 rows x e-quarter [w*128, w*128+128): acc[mt][nt], row mt*16+4lg+r, col nt*16+li
    f32x4 acc[4][8];
    #pragma unroll
    for (int mt = 0; mt < 4; ++mt)
        #pragma unroll
        for (int nt = 0; nt < 8; ++nt) acc[mt][nt] = (f32x4){0.f,0.f,0.f,0.f};
    float mrun = -1e30f, srun = 0.0f;

    stage(0, 0);
    gload16(mkb + tid*4,        (char*)maskL + w*1024);
    gload16(mkb + 1024 + tid*4, (char*)maskL + 4096 + w*1024);
    stage(KT, 1);
    VMCNT16;     // buf0 + mask landed; buf1's 16 still flying
    SBAR;

    const int key = li & 7;                 // A swizzle key
    const int keyT = (li >> 1) & 3;         // T swizzle key for PV reads
    for (int jt = 0; jt < 64; ++jt){
        const int bs = jt & 1;
        const short* Ac = &A_t[bs][0];
        const short* Tc = &T_t[bs][0];
        const int j0 = jt*KT;

        f32x4 mk0 = *(const f32x4*)&maskL[j0 + 4*lg];
        f32x4 mk1 = *(const f32x4*)&maskL[j0 + 16 + 4*lg];

        // ---- S^T for this wave's 16 rows (r7-verbatim) ----
        f32x4 s0a = (f32x4){0.f,0.f,0.f,0.f}, s0b = s0a, s1a = s0a, s1b = s0a;
        __builtin_amdgcn_s_setprio(1);
        #pragma unroll
        for (int ks = 0; ks < 8; ++ks){
            short8v a = *(const short8v*)&Ac[li*512 + (((ks*4 + lg)^key)*8)];
            s0a = __builtin_amdgcn_mfma_f32_16x16x32_bf16(a, qf[ks], s0a, 0, 0, 0);
        }
        #pragma unroll
        for (int ks = 8; ks < 16; ++ks){
            short8v a = *(const short8v*)&Ac[li*512 + (((ks*4 + lg)^key)*8)];
            s0b = __builtin_amdgcn_mfma_f32_16x16x32_bf16(a, qf[ks], s0b, 0, 0, 0);
        }
        #pragma unroll
        for (int ks = 0; ks < 8; ++ks){
            short8v a = *(const short8v*)&Ac[(li+16)*512 + (((ks*4 + lg)^key)*8)];
            s1a = __builtin_amdgcn_mfma_f32_16x16x32_bf16(a, qf[ks], s1a, 0, 0, 0);
        }
        #pragma unroll
        for (int ks = 8; ks < 16; ++ks){
            short8v a = *(const short8v*)&Ac[(li+16)*512 + (((ks*4 + lg)^key)*8)];
            s1b = __builtin_amdgcn_mfma_f32_16x16x32_bf16(a, qf[ks], s1b, 0, 0, 0);
        }
        __builtin_amdgcn_s_setprio(0);

        float sv[8];
        #pragma unroll
        for (int r = 0; r < 4; ++r){
            sv[r]     = s0a[r] + s0b[r] + (mk0[r] - 1.0f)*1e10f;
            sv[4 + r] = s1a[r] + s1b[r] + (mk1[r] - 1.0f)*1e10f;
        }
        float pmax = sv[0];
        #pragma unroll
        for (int k = 1; k < 8; ++k) pmax = fmaxf(pmax, sv[k]);
        pmax = fmaxf(pmax, __shfl_xor(pmax, 16));
        pmax = fmaxf(pmax, __shfl_xor(pmax, 32));
        float mnew = fmaxf(mrun, pmax);
        float al = __expf(mrun - mnew);
        float p[8]; float psum = 0.f;
        #pragma unroll
        for (int k = 0; k < 8; ++k){ p[k] = __expf(sv[k] - mnew); psum += p[k]; }
        psum += __shfl_xor(psum, 16);
        psum += __shfl_xor(psum, 32);
        srun = srun*al + psum;
        mrun = mnew;

        // publish P (bf16), al, and rescale-needed flag
        #pragma unroll
        for (int s2 = 0; s2 < 2; ++s2)
            #pragma unroll
            for (int k = 0; k < 2; ++k){
                unsigned lo2 = f2bf(p[s2*4 + 2*k]);
                unsigned hi2 = f2bf(p[s2*4 + 2*k + 1]);
                *(unsigned*)&P_lds[w][li][s2*16 + 4*lg + 2*k] = lo2 | (hi2 << 16);
            }
        if (lg == 0) alB[w*16 + li] = al;
        bool need = !__all(al == 1.0f);
        if (lane == 0) flagB[w] = need ? 1 : 0;

        SBAR;   // P/al/flags visible to all waves

        // ---- PV: all 64 rows x e-quarter [w*128 .. +128) ----
        if (flagB[0] | flagB[1] | flagB[2] | flagB[3]){
            #pragma unroll
            for (int mt = 0; mt < 4; ++mt){
                f32x4 alr = *(const f32x4*)&alB[mt*16 + 4*lg];
                #pragma unroll
                for (int nt = 0; nt < 8; ++nt)
                    #pragma unroll
                    for (int r = 0; r < 4; ++r) acc[mt][nt][r] *= alr[r];
            }
        }
        short8v pa[4];
        #pragma unroll
        for (int mt = 0; mt < 4; ++mt)
            pa[mt] = *(const short8v*)&P_lds[mt][li][lg*8];
        __builtin_amdgcn_s_setprio(1);
        #pragma unroll
        for (int nt = 0; nt < 8; ++nt){
            int e_local = (w*8 + nt)*16 + li;          // e within [0,512)
            short8v vf = *(const short8v*)&Tc[e_local*KT + ((lg ^ keyT)*8)];
            #pragma unroll
            for (int mt = 0; mt < 4; ++mt)
                acc[mt][nt] = __builtin_amdgcn_mfma_f32_16x16x32_bf16(pa[mt], vf, acc[mt][nt], 0, 0, 0);
        }
        __builtin_amdgcn_s_setprio(0);

        SBAR;                               // all reads of buf bs + P done
        if (jt + 2 < 64){ stage((jt+2)*KT, bs); VMCNT16; }
        else if (jt == 62){ VMCNT0; }
        SBAR;                               // next buffer ready
    }

    // final 1/s per row via LDS broadcast
    if (lg == 0) sB[w*16 + li] = srun;
    SBAR;
    #pragma unroll
    for (int mt = 0; mt < 4; ++mt){
        f32x4 s4 = *(const f32x4*)&sB[mt*16 + 4*lg];
        f32x4 inv;
        #pragma unroll
        for (int r = 0; r < 4; ++r) inv[r] = 1.0f / s4[r];
        #pragma unroll
        for (int nt = 0; nt < 8; ++nt)
            #pragma unroll
            for (int r = 0; r < 4; ++r)
                out[(size_t)(b*LQ + i0 + mt*16 + 4*lg + r)*1536 + w*128 + nt*16 + li]
                    = acc[mt][nt][r]*inv[r];
    }

    // fused q passthrough + mv broadcast for this block's 64 rows
    {
        const float4* q4  = (const float4*)qf32;
        const float4* mv4 = (const float4*)mv;
        float4* o4 = (float4*)out;
        #pragma unroll 4
        for (int idx = tid; idx < 64*128; idx += 256){
            int row = idx >> 7, c = idx & 127;
            size_t grow = (size_t)b*LQ + qt*64 + row;
            o4[grow*384 + 128 + c] = q4[grow*128 + c];
            o4[grow*384 + 256 + c] = mv4[b*128 + c];
        }
    }
}

extern "C" void kernel_launch(void* const* d_in, const int* in_sizes, int n_in,
                              void* d_out, int out_size, void* d_ws, size_t ws_size,
                              hipStream_t stream){
    const float* q     = (const float*)d_in[0];
    const float* v     = (const float*)d_in[1];
    const float* vmask = (const float*)d_in[2];
    const float* kern  = (const float*)d_in[3];
    float* out = (float*)d_out;
    char* ws = (char*)d_ws;

    const size_t SZ_QW = (size_t)NB*LQ*DOUT*2;       // 16 MB
    unsigned short* qw  = (unsigned short*)(ws);
    unsigned short* vbf = (unsigned short*)(ws + SZ_QW);
    unsigned short* vT  = (unsigned short*)(ws + 2*SZ_QW);
    unsigned short* kT  = (unsigned short*)(ws + 3*SZ_QW);
    float* mv   = (float*)(ws + 3*SZ_QW + 524288);
    float* part = (float*)(ws + 3*SZ_QW + 524288 + 16384);

    hipLaunchKernelGGL(prep_kT,  dim3(16,16),   dim3(256), 0, stream, kern, kT);
    hipLaunchKernelGGL(prep_v,   dim3(64,16,8), dim3(256), 0, stream, v, vmask, vbf, vT, part);
    hipLaunchKernelGGL(mv_final, dim3(8),       dim3(512), 0, stream, part, mv);
    hipLaunchKernelGGL(gemm_qw,  dim3(512),     dim3(256), 0, stream, q, kT, qw);
    hipLaunchKernelGGL(flash,    dim3(256),     dim3(256), 0, stream, qw, vbf, vT, vmask, q, mv, out);
}

// Round 10
// 251.721 us; speedup vs baseline: 4.0399x; 1.2014x over previous
//
#include <hip/hip_runtime.h>
#include <stdint.h>

// Problem: B=8, Lq=Lv=2048, Din=Dout=512, all f32 in/out.
// out[b][l][0:512)=o, [512:1024)=q, [1024:1536)=mv broadcast.
// Flash v10: 8-wave specialized block (512 thr, 1 blk/CU, 2 waves/SIMD).
// Waves 0-3 (S-role): S MFMAs + softmax for 16 rows each, publish P/al
// (parity-double-buffered). Waves 4-7 (PV-role): r9 P-broadcast PV, one
// 128-e quarter each over all 64 rows. S runs 1 tile ahead of PV.
// Staging split A-early/T-late keeps the 2-deep vmcnt landing invariant.

typedef __attribute__((ext_vector_type(8))) short short8v;
typedef __attribute__((ext_vector_type(4))) float f32x4;

#define LQ 2048
#define LV 2048
#define DIN 512
#define DOUT 512
#define NB 8
#define KT 32   // KV tile

__device__ __forceinline__ unsigned short f2bf(float x){
    union { float f; unsigned u; } v; v.f = x;
    unsigned r = v.u + 0x7fffu + ((v.u >> 16) & 1u);
    return (unsigned short)(r >> 16);
}

__device__ __forceinline__ void gload16(const void* g, void* l){
    __builtin_amdgcn_global_load_lds((const __attribute__((address_space(1))) void*)g,
                                     (__attribute__((address_space(3))) void*)l, 16, 0, 0);
}

#define SBAR   do{ __builtin_amdgcn_s_barrier(); __builtin_amdgcn_sched_barrier(0); }while(0)
#define LGKM0  do{ asm volatile("s_waitcnt lgkmcnt(0)" ::: "memory"); \
                   __builtin_amdgcn_sched_barrier(0); }while(0)
#define VMCNT4 do{ asm volatile("s_waitcnt vmcnt(4)" ::: "memory"); \
                   __builtin_amdgcn_sched_barrier(0); }while(0)
#define VMCNT0 do{ asm volatile("s_waitcnt vmcnt(0)" ::: "memory"); \
                   __builtin_amdgcn_sched_barrier(0); }while(0)

// kernel [DIN][DOUT] f32 -> kT [DOUT][DIN] bf16, scaled by 0.1 (folds the /10)
__global__ void prep_kT(const float* __restrict__ k, unsigned short* __restrict__ kT){
    __shared__ float tile[32][33];
    int tx = threadIdx.x & 31, ty = threadIdx.x >> 5;
    int kb = blockIdx.x, eb = blockIdx.y;
    #pragma unroll
    for (int p = 0; p < 4; ++p){
        int r = ty + p*8;
        tile[r][tx] = k[(size_t)(kb*32 + r)*DOUT + eb*32 + tx];
    }
    __syncthreads();
    #pragma unroll
    for (int p = 0; p < 4; ++p){
        int r = ty + p*8;
        kT[(size_t)(eb*32 + r)*DIN + kb*32 + tx] = f2bf(tile[tx][r] * 0.1f);
    }
}

// v f32 -> v bf16 (natural [b][j][e]) and vT bf16 ([b][e][j]) + masked-max partials
__global__ void prep_v(const float* __restrict__ v, const float* __restrict__ mask,
                       unsigned short* __restrict__ vbf, unsigned short* __restrict__ vT,
                       float* __restrict__ part){
    __shared__ float tile[32][33];
    __shared__ float pmax_l[8][33];
    int tx = threadIdx.x & 31, ty = threadIdx.x >> 5;
    int jb = blockIdx.x, eb = blockIdx.y, b = blockIdx.z;
    const size_t vbase = (size_t)b*LV*DOUT;
    #pragma unroll
    for (int p = 0; p < 4; ++p){
        int r = ty + p*8;
        size_t idx = vbase + (size_t)(jb*32 + r)*DOUT + eb*32 + tx;
        float val = v[idx];
        tile[r][tx] = val;
        vbf[idx] = f2bf(val);
    }
    __syncthreads();
    const size_t tbase = (size_t)b*DOUT*LV;
    #pragma unroll
    for (int p = 0; p < 4; ++p){
        int r = ty + p*8;
        vT[tbase + (size_t)(eb*32 + r)*LV + jb*32 + tx] = f2bf(tile[tx][r]);
    }
    float m = -3e38f;
    #pragma unroll
    for (int k2 = 0; k2 < 4; ++k2){
        int j = ty*4 + k2;
        float msk = mask[b*LV + jb*32 + j];
        m = fmaxf(m, tile[j][tx] - (1.0f - msk)*1e10f);
    }
    pmax_l[ty][tx] = m;
    __syncthreads();
    if (ty == 0){
        float mm = pmax_l[0][tx];
        #pragma unroll
        for (int c = 1; c < 8; ++c) mm = fmaxf(mm, pmax_l[c][tx]);
        part[((size_t)b*64 + jb)*DOUT + eb*32 + tx] = mm;
    }
}

__global__ void mv_final(const float* __restrict__ part, float* __restrict__ mv){
    int b = blockIdx.x; int e = threadIdx.x;
    float m = -3e38f;
    #pragma unroll
    for (int c = 0; c < 64; ++c) m = fmaxf(m, part[((size_t)b*64 + c)*DOUT + e]);
    mv[b*DOUT + e] = m;
}

// qw[b*Lq+l][e] = sum_d q[..][d] * kT[e][d]  (bf16 MFMA, f32 acc, bf16 out)
__global__ __launch_bounds__(256) void gemm_qw(const float* __restrict__ q,
                                               const unsigned short* __restrict__ kT,
                                               unsigned short* __restrict__ qw){
    int bid = blockIdx.x;
    int mb = bid >> 1, nb = bid & 1;
    int w = threadIdx.x >> 6, lane = threadIdx.x & 63;
    int li = lane & 15, lg = lane >> 4;
    int i0 = mb*64 + w*16;
    int n0 = nb*256;
    f32x4 acc[16];
    #pragma unroll
    for (int t = 0; t < 16; ++t) acc[t] = (f32x4){0.f,0.f,0.f,0.f};
    for (int ks = 0; ks < 16; ++ks){
        const float* qp = q + (size_t)(i0 + li)*DIN + ks*32 + lg*8;
        float4 lo = *(const float4*)qp;
        float4 hi = *(const float4*)(qp + 4);
        short8v af;
        af[0]=(short)f2bf(lo.x); af[1]=(short)f2bf(lo.y); af[2]=(short)f2bf(lo.z); af[3]=(short)f2bf(lo.w);
        af[4]=(short)f2bf(hi.x); af[5]=(short)f2bf(hi.y); af[6]=(short)f2bf(hi.z); af[7]=(short)f2bf(hi.w);
        #pragma unroll
        for (int t = 0; t < 16; ++t){
            short8v bf = *(const short8v*)(kT + (size_t)(n0 + t*16 + li)*DIN + ks*32 + lg*8);
            acc[t] = __builtin_amdgcn_mfma_f32_16x16x32_bf16(af, bf, acc[t], 0, 0, 0);
        }
    }
    #pragma unroll
    for (int t = 0; t < 16; ++t)
        #pragma unroll
        for (int r = 0; r < 4; ++r)
            qw[(size_t)(i0 + 4*lg + r)*DOUT + n0 + t*16 + li] = f2bf(acc[t][r]);
}

__global__ __launch_bounds__(512, 1) void flash(const unsigned short* __restrict__ qw,
                                                const unsigned short* __restrict__ vbf,
                                                const unsigned short* __restrict__ vT,
                                                const float* __restrict__ mask,
                                                const float* __restrict__ qf32,
                                                const float* __restrict__ mv,
                                                float* __restrict__ out){
    __shared__ __align__(16) short A_t[2][KT*512];     // 2x32KB, [j][e] unit^(j&7)
    __shared__ __align__(16) short T_t[2][512*KT];     // 2x32KB, [e][j] slot^((e>>1)&3)
    __shared__ __align__(16) float maskL[2048];        // 8KB mask row
    __shared__ short P_lds[2][4][16][40];              // parity x S-wave x row x j
    __shared__ float alB[2][64];
    __shared__ float sB[64];
    __shared__ int   flagB[2][4];

    const int bid = blockIdx.x;
    const int b = bid & 7, qt = bid >> 3;   // batch -> XCD pin
    const int tid = threadIdx.x;
    const int w = tid >> 6, lane = tid & 63;
    const int li = lane & 15, lg = lane >> 4;
    const int i0 = qt*64;

    const unsigned short* vb  = vbf + (size_t)b*LV*DOUT;
    const unsigned short* vTb = vT  + (size_t)b*DOUT*LV;
    const float* mkb = mask + b*LV;

    // staging split across all 8 waves: wave w does A rows w*4..+3, T chunks w*4..+3
    auto stageA = [&](int j0g, int buf){
        #pragma unroll
        for (int p = 0; p < 4; ++p){
            int j = w*4 + p;
            gload16(vb + (size_t)(j0g + j)*DOUT + ((lane ^ (j&7))*8), &A_t[buf][j*512]);
        }
    };
    auto stageT = [&](int j0g, int buf){
        #pragma unroll
        for (int p = 0; p < 4; ++p){
            int c = w*4 + p;
            int e = c*16 + (lane >> 2);
            gload16(vTb + (size_t)e*LV + j0g + (((lane&3) ^ ((lane>>3)&3))*8),
                    &T_t[buf][c*512]);
        }
    };

    // prologue: A0,A1,T0,mask,T1 -> wait all but T1 landed
    stageA(0, 0); stageA(KT, 1); stageT(0, 0);
    gload16(mkb + w*256 + lane*4, (char*)maskL + w*1024);
    stageT(KT, 1);
    VMCNT4; SBAR;

    if (w < 4){
        // ================= S role: 16 rows i0+w*16+li =================
        short8v qf[16];
        const unsigned short* qrow = qw + (size_t)(b*LQ + i0 + w*16 + li)*DIN;
        #pragma unroll
        for (int ks = 0; ks < 16; ++ks)
            qf[ks] = *(const short8v*)(qrow + ks*32 + lg*8);
        float mrun = -1e30f, srun = 0.0f;
        const int key = li & 7;

        auto computeS = [&](int jn){
            const int pn = jn & 1;
            const short* Ac = &A_t[pn][0];
            const int j0 = jn*KT;
            f32x4 mk0 = *(const f32x4*)&maskL[j0 + 4*lg];
            f32x4 mk1 = *(const f32x4*)&maskL[j0 + 16 + 4*lg];

            f32x4 s0a = (f32x4){0.f,0.f,0.f,0.f}, s0b = s0a, s1a = s0a, s1b = s0a;
            __builtin_amdgcn_s_setprio(1);
            #pragma unroll
            for (int ks = 0; ks < 8; ++ks){
                short8v a = *(const short8v*)&Ac[li*512 + (((ks*4 + lg)^key)*8)];
                s0a = __builtin_amdgcn_mfma_f32_16x16x32_bf16(a, qf[ks], s0a, 0, 0, 0);
            }
            #pragma unroll
            for (int ks = 8; ks < 16; ++ks){
                short8v a = *(const short8v*)&Ac[li*512 + (((ks*4 + lg)^key)*8)];
                s0b = __builtin_amdgcn_mfma_f32_16x16x32_bf16(a, qf[ks], s0b, 0, 0, 0);
            }
            #pragma unroll
            for (int ks = 0; ks < 8; ++ks){
                short8v a = *(const short8v*)&Ac[(li+16)*512 + (((ks*4 + lg)^key)*8)];
                s1a = __builtin_amdgcn_mfma_f32_16x16x32_bf16(a, qf[ks], s1a, 0, 0, 0);
            }
            #pragma unroll
            for (int ks = 8; ks < 16; ++ks){
                short8v a = *(const short8v*)&Ac[(li+16)*512 + (((ks*4 + lg)^key)*8)];
                s1b = __builtin_amdgcn_mfma_f32_16x16x32_bf16(a, qf[ks], s1b, 0, 0, 0);
            }
            __builtin_amdgcn_s_setprio(0);

            float sv[8];
            #pragma unroll
            for (int r = 0; r < 4; ++r){
                sv[r]     = s0a[r] + s0b[r] + (mk0[r] - 1.0f)*1e10f;
                sv[4 + r] = s1a[r] + s1b[r] + (mk1[r] - 1.0f)*1e10f;
            }
            float pmax = sv[0];
            #pragma unroll
            for (int k = 1; k < 8; ++k) pmax = fmaxf(pmax, sv[k]);
            pmax = fmaxf(pmax, __shfl_xor(pmax, 16));
            pmax = fmaxf(pmax, __shfl_xor(pmax, 32));
            // defer-max (THR=8): skip rescale while max growth small
            bool skip = __all(pmax <= mrun + 8.0f);
            float al;
            if (skip){ al = 1.0f; }
            else { float mnew = fmaxf(mrun, pmax); al = __expf(mrun - mnew); mrun = mnew; }
            float p[8]; float psum = 0.f;
            #pragma unroll
            for (int k = 0; k < 8; ++k){ p[k] = __expf(sv[k] - mrun); psum += p[k]; }
            psum += __shfl_xor(psum, 16);
            psum += __shfl_xor(psum, 32);
            srun = srun*al + psum;

            #pragma unroll
            for (int s2 = 0; s2 < 2; ++s2)
                #pragma unroll
                for (int k = 0; k < 2; ++k){
                    unsigned lo2 = f2bf(p[s2*4 + 2*k]);
                    unsigned hi2 = f2bf(p[s2*4 + 2*k + 1]);
                    *(unsigned*)&P_lds[pn][w][li][s2*16 + 4*lg + 2*k] = lo2 | (hi2 << 16);
                }
            if (lg == 0) alB[pn][w*16 + li] = al;
            if (lane == 0) flagB[pn][w] = skip ? 0 : 1;
        };

        computeS(0);
        LGKM0; SBAR;                        // B0b: P(0) published

        for (int jt = 0; jt < 64; ++jt){
            if (jt + 2 < 64) stageA((jt+2)*KT, jt & 1);   // A(jt) dead
            if (jt < 63) computeS(jt + 1);
            LGKM0; SBAR;                    // B1: P(jt+1) published; PV(jt) done
            if (jt + 2 < 64){ stageT((jt+2)*KT, jt & 1); VMCNT4; }
            else if (jt == 62){ VMCNT0; }
            SBAR;                           // B2
        }

        if (lg == 0) sB[w*16 + li] = srun;
        LGKM0; SBAR;                        // BE

        // q passthrough + mv broadcast (S-waves = 256 threads)
        const float4* q4  = (const float4*)qf32;
        const float4* mv4 = (const float4*)mv;
        float4* o4 = (float4*)out;
        #pragma unroll 4
        for (int idx = w*64 + lane; idx < 64*128; idx += 256){
            int row = idx >> 7, c = idx & 127;
            size_t grow = (size_t)b*LQ + i0 + row;
            o4[grow*384 + 128 + c] = q4[grow*128 + c];
            o4[grow*384 + 256 + c] = mv4[b*128 + c];
        }
    } else {
        // ================= PV role: e-quarter [wp*128, +128), all 64 rows =================
        const int wp = w - 4;
        const int keyT = (li >> 1) & 3;
        f32x4 acc[4][8];
        #pragma unroll
        for (int mt = 0; mt < 4; ++mt)
            #pragma unroll
            for (int nt = 0; nt < 8; ++nt) acc[mt][nt] = (f32x4){0.f,0.f,0.f,0.f};

        SBAR;                               // B0b

        for (int jt = 0; jt < 64; ++jt){
            const int pc = jt & 1;
            if (jt + 2 < 64) stageA((jt+2)*KT, jt & 1);

            if (flagB[pc][0] | flagB[pc][1] | flagB[pc][2] | flagB[pc][3]){
                #pragma unroll
                for (int mt = 0; mt < 4; ++mt){
                    f32x4 alr = *(const f32x4*)&alB[pc][mt*16 + 4*lg];
                    #pragma unroll
                    for (int nt = 0; nt < 8; ++nt)
                        #pragma unroll
                        for (int r = 0; r < 4; ++r) acc[mt][nt][r] *= alr[r];
                }
            }
            short8v pa[4];
            #pragma unroll
            for (int mt = 0; mt < 4; ++mt)
                pa[mt] = *(const short8v*)&P_lds[pc][mt][li][lg*8];
            const short* Tc = &T_t[pc][0];
            __builtin_amdgcn_s_setprio(1);
            #pragma unroll
            for (int nt = 0; nt < 8; ++nt){
                int e_local = (wp*8 + nt)*16 + li;
                short8v vf = *(const short8v*)&Tc[e_local*KT + ((lg ^ keyT)*8)];
                #pragma unroll
                for (int mt = 0; mt < 4; ++mt)
                    acc[mt][nt] = __builtin_amdgcn_mfma_f32_16x16x32_bf16(pa[mt], vf, acc[mt][nt], 0, 0, 0);
            }
            __builtin_amdgcn_s_setprio(0);

            SBAR;                           // B1
            if (jt + 2 < 64){ stageT((jt+2)*KT, jt & 1); VMCNT4; }
            else if (jt == 62){ VMCNT0; }
            SBAR;                           // B2
        }

        SBAR;                               // BE: sB published

        #pragma unroll
        for (int mt = 0; mt < 4; ++mt){
            f32x4 s4 = *(const f32x4*)&sB[mt*16 + 4*lg];
            f32x4 inv;
            #pragma unroll
            for (int r = 0; r < 4; ++r) inv[r] = 1.0f / s4[r];
            #pragma unroll
            for (int nt = 0; nt < 8; ++nt)
                #pragma unroll
                for (int r = 0; r < 4; ++r)
                    out[(size_t)(b*LQ + i0 + mt*16 + 4*lg + r)*1536 + wp*128 + nt*16 + li]
                        = acc[mt][nt][r]*inv[r];
        }
    }
}

extern "C" void kernel_launch(void* const* d_in, const int* in_sizes, int n_in,
                              void* d_out, int out_size, void* d_ws, size_t ws_size,
                              hipStream_t stream){
    const float* q     = (const float*)d_in[0];
    const float* v     = (const float*)d_in[1];
    const float* vmask = (const float*)d_in[2];
    const float* kern  = (const float*)d_in[3];
    float* out = (float*)d_out;
    char* ws = (char*)d_ws;

    const size_t SZ_QW = (size_t)NB*LQ*DOUT*2;       // 16 MB
    unsigned short* qw  = (unsigned short*)(ws);
    unsigned short* vbf = (unsigned short*)(ws + SZ_QW);
    unsigned short* vT  = (unsigned short*)(ws + 2*SZ_QW);
    unsigned short* kT  = (unsigned short*)(ws + 3*SZ_QW);
    float* mv   = (float*)(ws + 3*SZ_QW + 524288);
    float* part = (float*)(ws + 3*SZ_QW + 524288 + 16384);

    hipLaunchKernelGGL(prep_kT,  dim3(16,16),   dim3(256), 0, stream, kern, kT);
    hipLaunchKernelGGL(prep_v,   dim3(64,16,8), dim3(256), 0, stream, v, vmask, vbf, vT, part);
    hipLaunchKernelGGL(mv_final, dim3(8),       dim3(512), 0, stream, part, mv);
    hipLaunchKernelGGL(gemm_qw,  dim3(512),     dim3(256), 0, stream, q, kT, qw);
    hipLaunchKernelGGL(flash,    dim3(256),     dim3(512), 0, stream, qw, vbf, vT, vmask, q, mv, out);
}